// Round 1
// baseline (396.649 us; speedup 1.0000x reference)
//
#include <hip/hip_runtime.h>

#define B_ 8
#define C_ 64
#define H_ 256
#define W_ 256
#define HW_ 65536
#define PLANE_ 33554432  // B*C*H*W

typedef __attribute__((ext_vector_type(8))) short short8;
typedef __attribute__((ext_vector_type(4))) float f32x4;

__device__ __forceinline__ unsigned short f2bf(float f){
  unsigned u = __float_as_uint(f);
  u += 0x7fffu + ((u >> 16) & 1u);
  return (unsigned short)(u >> 16);
}

// ---------------- kernel 1: QKV projection ----------------
// grid = B*H, 256 thr. Block (b,h): Out_p[o][w] = sum_i W_p[o][i]*x[b,i,h,w] + b_p[o]
__global__ __launch_bounds__(256) void proj_kernel(
    const float* __restrict__ x,
    const float* __restrict__ Wq, const float* __restrict__ bq,
    const float* __restrict__ Wk, const float* __restrict__ bk,
    const float* __restrict__ Wv, const float* __restrict__ bv,
    unsigned short* __restrict__ Qb, unsigned short* __restrict__ Kb,
    unsigned short* __restrict__ Vb)
{
  __shared__ unsigned short Xt[W_*64];      // [w][i] bf16, xor-swizzled (32 KB)
  __shared__ unsigned short Wl[3*64*64];    // [p][o][i] bf16, swizzled (24 KB)
  const int tid = threadIdx.x;
  const int lane = tid & 63;
  const int wv  = tid >> 6;
  const int q4 = lane >> 4, l16 = lane & 15;
  const int bid = blockIdx.x;
  const int b = bid >> 8, h = bid & 255;

  const float* wsrc[3] = {Wq, Wk, Wv};
  #pragma unroll
  for (int p=0;p<3;++p){
    const float* wp = wsrc[p];
    for (int idx=tid; idx<4096; idx+=256){
      int o = idx >> 6, i = idx & 63;
      Wl[p*4096 + o*64 + (i ^ ((o&7)<<3))] = f2bf(wp[idx]);
    }
  }
  {
    const float* xb = x + (size_t)b*C_*HW_ + (size_t)h*W_;
    #pragma unroll
    for (int it=0; it<16; ++it){
      int i = it*4 + wv;                       // channel row
      float4 v = *(const float4*)(xb + (size_t)i*HW_ + lane*4);
      float fv[4] = {v.x, v.y, v.z, v.w};
      #pragma unroll
      for (int k2=0;k2<4;++k2){
        int w = lane*4 + k2;
        int slot = (w&7) ^ ((w>>3)&7);
        Xt[w*64 + (i ^ (slot<<3))] = f2bf(fv[k2]);
      }
    }
  }
  __syncthreads();

  unsigned short* outp[3] = {Qb, Kb, Vb};
  const float* bsrc[3] = {bq, bk, bv};
  const size_t obase = (size_t)b*C_*HW_ + (size_t)h*W_;

  #pragma unroll
  for (int p=0;p<3;++p){
    short8 afr[4][2];
    #pragma unroll
    for (int mf=0;mf<4;++mf){
      #pragma unroll
      for (int kk=0;kk<2;++kk){
        int o = mf*16 + l16;
        int i = (32*kk + 8*q4) ^ ((o&7)<<3);
        afr[mf][kk] = *(const short8*)&Wl[p*4096 + o*64 + i];
      }
    }
    f32x4 acc[4][4];
    #pragma unroll
    for (int mf=0;mf<4;++mf){
      #pragma unroll
      for (int nf=0;nf<4;++nf){ f32x4 z = {0.f,0.f,0.f,0.f}; acc[mf][nf] = z; }
    }
    #pragma unroll
    for (int nf=0;nf<4;++nf){
      int w = wv*64 + nf*16 + l16;
      int slot = (w&7) ^ ((w>>3)&7);
      #pragma unroll
      for (int kk=0;kk<2;++kk){
        short8 bfr = *(const short8*)&Xt[w*64 + ((32*kk + 8*q4) ^ (slot<<3))];
        #pragma unroll
        for (int mf=0;mf<4;++mf)
          acc[mf][nf] = __builtin_amdgcn_mfma_f32_16x16x32_bf16(afr[mf][kk], bfr, acc[mf][nf], 0,0,0);
      }
    }
    unsigned short* op = outp[p];
    const float* bp = bsrc[p];
    #pragma unroll
    for (int mf=0;mf<4;++mf){
      #pragma unroll
      for (int r=0;r<4;++r){
        int o = mf*16 + 4*q4 + r;
        float bias = bp[o];
        #pragma unroll
        for (int nf=0;nf<4;++nf){
          int w = wv*64 + nf*16 + l16;
          op[obase + (size_t)o*HW_ + w] = f2bf(acc[mf][nf][r] + bias);
        }
      }
    }
  }
}

// ---------------- kernel 2: in-place V transpose (per (b,c) 256x256) ----------------
__global__ __launch_bounds__(256) void transpose_v(unsigned short* __restrict__ Vb)
{
  const int pi[10] = {0,0,0,0,1,1,1,2,2,3};
  const int pj[10] = {0,1,2,3,1,2,3,2,3,3};
  __shared__ unsigned short tA[64*65];
  __shared__ unsigned short tB[64*65];
  int t = threadIdx.x;
  int bid = blockIdx.x;
  int bc = bid / 10, pr = bid - bc*10;
  int ti = pi[pr], tj = pj[pr];
  unsigned short* base = Vb + (size_t)bc*HW_;
  int diag = (ti == tj);
  #pragma unroll
  for (int k=0;k<2;++k){
    int flat = t + k*256;
    int i = flat >> 3, j = (flat & 7)*8;
    int4 va = *(const int4*)(base + (size_t)(ti*64+i)*256 + tj*64 + j);
    const unsigned short* pa = (const unsigned short*)&va;
    #pragma unroll
    for (int e=0;e<8;++e) tA[i*65 + j + e] = pa[e];
    if (!diag){
      int4 vb2 = *(const int4*)(base + (size_t)(tj*64+i)*256 + ti*64 + j);
      const unsigned short* pb = (const unsigned short*)&vb2;
      #pragma unroll
      for (int e=0;e<8;++e) tB[i*65 + j + e] = pb[e];
    }
  }
  __syncthreads();
  #pragma unroll
  for (int k=0;k<2;++k){
    int flat = t + k*256;
    int i = flat >> 3, j = (flat & 7)*8;
    int4 vo; unsigned short* po = (unsigned short*)&vo;
    #pragma unroll
    for (int e=0;e<8;++e) po[e] = tA[(j+e)*65 + i];
    *(int4*)(base + (size_t)(tj*64+i)*256 + ti*64 + j) = vo;
    if (!diag){
      int4 vo2; unsigned short* po2 = (unsigned short*)&vo2;
      #pragma unroll
      for (int e=0;e<8;++e) po2[e] = tB[(j+e)*65 + i];
      *(int4*)(base + (size_t)(ti*64+i)*256 + tj*64 + j) = vo2;
    }
  }
}

// ---------------- kernel 3: attention + BN + PReLU ----------------
__device__ __forceinline__ void copy_tile_swz(unsigned short* dst, const unsigned short* src, int tid){
  const int4* s = (const int4*)src;
  int4* d = (int4*)dst;
  #pragma unroll
  for (int k=0;k<8;++k){
    int f = tid + k*256;
    d[f ^ ((f>>5)&7)] = s[f];   // byte ^= (row&7)<<4 at int4 granularity
  }
}

__global__ __launch_bounds__(256) void attn_kernel(
    const unsigned short* __restrict__ Qb, const unsigned short* __restrict__ Kb,
    const unsigned short* __restrict__ Vtb,
    const float* __restrict__ gamma, const float* __restrict__ beta,
    const float* __restrict__ rmean, const float* __restrict__ rvar,
    const float* __restrict__ alphaP,
    float* __restrict__ out)
{
  __shared__ unsigned short s_q [64*256];  // Q tile, later reused for P (32 KB)
  __shared__ unsigned short s_kv[64*256];  // K tiles, then Vt tiles     (32 KB)
  const int tid = threadIdx.x;
  const int lane = tid & 63;
  const int wv = tid >> 6;
  const int q4 = lane >> 4, l16 = lane & 15;
  const int bid = blockIdx.x;
  const int bc = bid >> 2, ht = bid & 3;
  const int c = bc & 63;

  const unsigned short* Qp = Qb  + (size_t)bc*HW_ + ht*64*W_;
  const unsigned short* Kp = Kb  + (size_t)bc*HW_;
  const unsigned short* Vp = Vtb + (size_t)bc*HW_;

  copy_tile_swz(s_q,  Qp, tid);
  copy_tile_swz(s_kv, Kp, tid);
  __syncthreads();

  short8 aq[8];
  {
    int row = wv*16 + l16;
    int sw = (row&7)<<3;
    #pragma unroll
    for (int kk=0;kk<8;++kk)
      aq[kk] = *(const short8*)&s_q[row*256 + ((8*q4 + 32*kk) ^ sw)];
  }

  f32x4 sa[16];
  #pragma unroll
  for (int f=0;f<16;++f){ f32x4 z = {0.f,0.f,0.f,0.f}; sa[f] = z; }

  #pragma unroll
  for (int gt=0; gt<4; ++gt){
    #pragma unroll
    for (int nf=0;nf<4;++nf){
      int g = nf*16 + l16;
      int sw = (g&7)<<3;
      int f = gt*4 + nf;
      #pragma unroll
      for (int kk=0;kk<8;++kk){
        short8 bf_ = *(const short8*)&s_kv[g*256 + ((8*q4 + 32*kk) ^ sw)];
        sa[f] = __builtin_amdgcn_mfma_f32_16x16x32_bf16(aq[kk], bf_, sa[f], 0,0,0);
      }
    }
    __syncthreads();
    if (gt < 3){
      copy_tile_swz(s_kv, Kp + (gt+1)*64*W_, tid);
      __syncthreads();
    }
  }

  // wave-local softmax over g (rows live in 16-lane groups)
  float mrow[4], rden[4], psum[4];
  #pragma unroll
  for (int r=0;r<4;++r){
    float m = -3.0e38f;
    #pragma unroll
    for (int f=0;f<16;++f) m = fmaxf(m, sa[f][r]);
    m = fmaxf(m, __shfl_xor(m, 1, 16));
    m = fmaxf(m, __shfl_xor(m, 2, 16));
    m = fmaxf(m, __shfl_xor(m, 4, 16));
    m = fmaxf(m, __shfl_xor(m, 8, 16));
    mrow[r] = m;
    psum[r] = 0.f;
  }
  const float cs = 0.25f * 1.4426950408889634f;  // /H^0.25 folded, exp->exp2
  #pragma unroll
  for (int f=0;f<16;++f){
    #pragma unroll
    for (int r=0;r<4;++r){
      float pv = exp2f((sa[f][r] - mrow[r]) * cs);
      sa[f][r] = pv;
      psum[r] += pv;
    }
  }
  #pragma unroll
  for (int r=0;r<4;++r){
    float s = psum[r];
    s += __shfl_xor(s, 1, 16);
    s += __shfl_xor(s, 2, 16);
    s += __shfl_xor(s, 4, 16);
    s += __shfl_xor(s, 8, 16);
    rden[r] = 1.0f / s;
  }
  // P (unnormalized, bf16) -> s_q (Q is already in regs)
  #pragma unroll
  for (int r=0;r<4;++r){
    int row = wv*16 + 4*q4 + r;
    int sw = (row&7)<<3;
    #pragma unroll
    for (int f=0;f<16;++f){
      int g = l16 + 16*f;
      s_q[row*256 + (g ^ sw)] = f2bf(sa[f][r]);
    }
  }

  short8 ap[8];
  {
    int row = wv*16 + l16;
    int sw = (row&7)<<3;
    #pragma unroll
    for (int kk=0;kk<8;++kk)
      ap[kk] = *(const short8*)&s_q[row*256 + ((8*q4 + 32*kk) ^ sw)];
  }

  f32x4 oa[16];
  #pragma unroll
  for (int f=0;f<16;++f){ f32x4 z = {0.f,0.f,0.f,0.f}; oa[f] = z; }

  #pragma unroll
  for (int wt=0; wt<4; ++wt){
    __syncthreads();
    copy_tile_swz(s_kv, Vp + wt*64*W_, tid);
    __syncthreads();
    #pragma unroll
    for (int nf=0;nf<4;++nf){
      int wl = nf*16 + l16;
      int sw = (wl&7)<<3;
      int fo = wt*4 + nf;
      #pragma unroll
      for (int kk=0;kk<8;++kk){
        short8 bf_ = *(const short8*)&s_kv[wl*256 + ((8*q4 + 32*kk) ^ sw)];
        oa[fo] = __builtin_amdgcn_mfma_f32_16x16x32_bf16(ap[kk], bf_, oa[fo], 0,0,0);
      }
    }
  }

  // epilogue: softmax denom + BatchNorm(eval) + PReLU
  float inv   = gamma[c] / sqrtf(rvar[c] + 1e-5f);
  float shift = beta[c] - rmean[c]*inv;
  float al    = alphaP[0];
  float* ob = out + (size_t)bc*HW_ + ht*64*W_;
  #pragma unroll
  for (int wt=0; wt<4; ++wt){
    #pragma unroll
    for (int nf=0; nf<4; ++nf){
      int fo = wt*4 + nf;
      int w = wt*64 + nf*16 + l16;
      #pragma unroll
      for (int r=0;r<4;++r){
        int row = wv*16 + 4*q4 + r;
        float v = oa[fo][r] * rden[r];
        v = v*inv + shift;
        v = (v >= 0.f) ? v : al*v;
        ob[(size_t)row*W_ + w] = v;
      }
    }
  }
}

extern "C" void kernel_launch(void* const* d_in, const int* in_sizes, int n_in,
                              void* d_out, int out_size, void* d_ws, size_t ws_size,
                              hipStream_t stream)
{
  const float* x     = (const float*)d_in[0];
  const float* Wq    = (const float*)d_in[1];
  const float* bq    = (const float*)d_in[2];
  const float* Wk    = (const float*)d_in[3];
  const float* bk    = (const float*)d_in[4];
  const float* Wv    = (const float*)d_in[5];
  const float* bv    = (const float*)d_in[6];
  const float* gamma = (const float*)d_in[7];
  const float* beta  = (const float*)d_in[8];
  const float* rmean = (const float*)d_in[9];
  const float* rvar  = (const float*)d_in[10];
  const float* alpha = (const float*)d_in[11];
  float* out = (float*)d_out;

  unsigned short* Qb = (unsigned short*)d_ws;          // 64 MB bf16
  unsigned short* Kb = Qb + (size_t)PLANE_;            // 64 MB bf16
  unsigned short* Vb = Kb + (size_t)PLANE_;            // 64 MB bf16 (becomes V^T)

  proj_kernel<<<B_*H_, 256, 0, stream>>>(x, Wq,bq, Wk,bk, Wv,bv, Qb, Kb, Vb);
  transpose_v<<<B_*C_*10, 256, 0, stream>>>(Vb);
  attn_kernel<<<B_*C_*4, 256, 0, stream>>>(Qb, Kb, Vb, gamma, beta, rmean, rvar, alpha, out);
}